// Round 1
// baseline (68226.343 us; speedup 1.0000x reference)
//
#include <hip/hip_runtime.h>
#include <hip/hip_bf16.h>
#include <hip/hip_cooperative_groups.h>

namespace cg = cooperative_groups;

#define TSTEPS 512
#define BATCH  64
#define HDIM   1024
#define NROWS  (TSTEPS*BATCH)   // 32768

__device__ __forceinline__ unsigned short f2bf(float f){
    unsigned u = __float_as_uint(f);
    u += 0x7fffu + ((u >> 16) & 1u);
    return (unsigned short)(u >> 16);
}
__device__ __forceinline__ float bf2f(unsigned short s){
    return __uint_as_float(((unsigned)s) << 16);
}

template<typename GT> struct GIO;
template<> struct GIO<float>{
    static __device__ __forceinline__ void st(float* p, float a, float b, float c, float d){
        *reinterpret_cast<float4*>(p) = make_float4(a,b,c,d);
    }
    static __device__ __forceinline__ float4 ld(const float* p){
        return *reinterpret_cast<const float4*>(p);
    }
};
template<> struct GIO<unsigned short>{
    static __device__ __forceinline__ void st(unsigned short* p, float a, float b, float c, float d){
        ushort4 u; u.x=f2bf(a); u.y=f2bf(b); u.z=f2bf(c); u.w=f2bf(d);
        *reinterpret_cast<ushort4*>(p) = u;
    }
    static __device__ __forceinline__ float4 ld(const unsigned short* p){
        ushort4 u = *reinterpret_cast<const ushort4*>(p);
        return make_float4(bf2f(u.x),bf2f(u.y),bf2f(u.z),bf2f(u.w));
    }
};

// ---------------------------------------------------------------------------
// GEMM: gp[t][bid][b][j] = sum_k X[t*64+b][k] * W[k][col(bid,j)] + bias
// col(bid,j) = (j/4)*1024 + bid*4 + (j%4)   (j = gate*4 + hj)
// Tile 128 rows x 128 n', BK=16, 256 threads, 8x8 microtile.
// ---------------------------------------------------------------------------
template<typename GT>
__global__ __launch_bounds__(256)
void gemm_xw(const float* __restrict__ X, const float* __restrict__ W,
             const float* __restrict__ bias, GT* __restrict__ gp)
{
    __shared__ float Alds[16][128];
    __shared__ float Blds[16][128];
    const int tid = threadIdx.x;
    const int tx = tid & 15;
    const int ty = tid >> 4;
    const int row0 = blockIdx.y * 128;
    const int np0  = blockIdx.x * 128;

    // A staging: thread -> (row = tid/2, k-half = (tid&1)*8)
    const int arow = tid >> 1;
    const int akh  = (tid & 1) * 8;
    const float* Aptr = X + (size_t)(row0 + arow) * 1024 + akh;

    // B staging: thread -> (k row = tid/16, n' run of 8 = (tid&15)*8)
    const int bkk  = tid >> 4;
    const int npl  = (tid & 15) * 8;
    const int bidS = (np0 + npl) >> 4;
    const int jbS  = npl & 15;             // 0 or 8
    const int g1   = jbS >> 2;             // 0 or 2
    const float* BptrA = W + (size_t)bkk*4096 + (size_t)g1*1024 + bidS*4;
    const float* BptrB = W + (size_t)bkk*4096 + (size_t)(g1+1)*1024 + bidS*4;

    float acc[8][8];
    #pragma unroll
    for (int r=0;r<8;++r){
        #pragma unroll
        for (int q=0;q<8;++q) acc[r][q]=0.f;
    }

    for (int k0=0; k0<1024; k0+=16){
        __syncthreads();
        float4 xa = *reinterpret_cast<const float4*>(Aptr + k0);
        float4 xb = *reinterpret_cast<const float4*>(Aptr + k0 + 4);
        Alds[akh+0][arow]=xa.x; Alds[akh+1][arow]=xa.y; Alds[akh+2][arow]=xa.z; Alds[akh+3][arow]=xa.w;
        Alds[akh+4][arow]=xb.x; Alds[akh+5][arow]=xb.y; Alds[akh+6][arow]=xb.z; Alds[akh+7][arow]=xb.w;
        float4 w0 = *reinterpret_cast<const float4*>(BptrA + (size_t)k0*4096);
        float4 w1 = *reinterpret_cast<const float4*>(BptrB + (size_t)k0*4096);
        *reinterpret_cast<float4*>(&Blds[bkk][npl])   = w0;
        *reinterpret_cast<float4*>(&Blds[bkk][npl+4]) = w1;
        __syncthreads();
        #pragma unroll
        for (int kk=0; kk<16; ++kk){
            float4 a0 = *reinterpret_cast<float4*>(&Alds[kk][ty*8]);
            float4 a1 = *reinterpret_cast<float4*>(&Alds[kk][ty*8+4]);
            float4 b0 = *reinterpret_cast<float4*>(&Blds[kk][tx*8]);
            float4 b1 = *reinterpret_cast<float4*>(&Blds[kk][tx*8+4]);
            float av[8]={a0.x,a0.y,a0.z,a0.w,a1.x,a1.y,a1.z,a1.w};
            float bv[8]={b0.x,b0.y,b0.z,b0.w,b1.x,b1.y,b1.z,b1.w};
            #pragma unroll
            for (int r=0;r<8;++r){
                #pragma unroll
                for (int q=0;q<8;++q) acc[r][q] += av[r]*bv[q];
            }
        }
    }

    const int bid = (np0 + tx*8) >> 4;
    const int jb  = (tx*8) & 15;
    float bv[8];
    #pragma unroll
    for (int q=0;q<8;++q){
        int j = jb + q;
        bv[q] = bias[(j>>2)*1024 + bid*4 + (j&3)];
    }
    #pragma unroll
    for (int r=0;r<8;++r){
        int m = row0 + ty*8 + r;
        int tt = m >> 6, b = m & 63;
        size_t base = (((size_t)tt*256 + bid)*64 + b)*16 + jb;
        GIO<GT>::st(gp+base,   acc[r][0]+bv[0], acc[r][1]+bv[1], acc[r][2]+bv[2], acc[r][3]+bv[3]);
        GIO<GT>::st(gp+base+4, acc[r][4]+bv[4], acc[r][5]+bv[5], acc[r][6]+bv[6], acc[r][7]+bv[7]);
    }
}

// ---------------------------------------------------------------------------
// Persistent recurrence. 256 blocks (1/CU), block owns h-cols [bidx*4, bidx*4+4).
// W_hh slice (16 gate cols x 1024 K) lives in LDS. h kept transposed [H][B]
// double-buffered in global. One grid sync per time step.
// ---------------------------------------------------------------------------
template<typename GT>
__global__ __launch_bounds__(256)
void lstm_seq(const GT* __restrict__ gp, const float* __restrict__ Whh,
              float* __restrict__ out, float* __restrict__ hta,
              float* __restrict__ htb, float* __restrict__ ct,
              float* __restrict__ hn, float* __restrict__ cn)
{
    __shared__ float Wlds[1024*16];      // 64 KB   [k][j]
    __shared__ float hstage[4][2048];    // 32 KB   per-wave [32k][64b] chunk
    __shared__ float pacc[4][1024];      // 16 KB   per-wave partial gates [b][j]
    __shared__ float xwlds[1024];        //  4 KB   xW[t] slice [b][j]
    __shared__ float hout[256];          //  1 KB   h_new [b][hj]

    const int tid  = threadIdx.x;
    const int bidx = blockIdx.x;
    const int wave = tid >> 6;
    const int lane = tid & 63;

    {   // load W_hh slice: Wlds[k][j] = Whh[k][ (j/4)*1024 + bidx*4 + (j%4) ]
        const int j = tid & 15;
        const int col = (j>>2)*1024 + bidx*4 + (j&3);
        for (int k = tid>>4; k < 1024; k += 16)
            Wlds[k*16 + j] = Whh[(size_t)k*4096 + col];
    }
    {   // zero-init h and c for our columns
        const int hcolg = bidx*4 + (tid>>6);
        hta[hcolg*64 + (tid&63)] = 0.f;
        ct [hcolg*64 + (tid&63)] = 0.f;
    }
    cg::this_grid().sync();

    float* hcur = hta;
    float* hnxt = htb;

    const int c0 = (lane & 3) << 2;      // 4 gate-cols per lane
    const int b0 = (lane >> 2) << 2;     // 4 batches per lane
    const int kbase = wave << 8;         // wave's K range [kbase, kbase+256)
    const int bq = tid & 63;             // phase-C batch
    const int hj = tid >> 6;             // phase-C h-col within block

    for (int t=0; t<TSTEPS; ++t){
        {   // stage this block's xW[t] slice (coalesced 4 KB)
            float4 v = GIO<GT>::ld(gp + ((size_t)t*256 + bidx)*1024 + tid*4);
            *reinterpret_cast<float4*>(&xwlds[tid*4]) = v;
        }
        float acc[4][4];
        #pragma unroll
        for (int i=0;i<4;++i){acc[i][0]=0.f;acc[i][1]=0.f;acc[i][2]=0.f;acc[i][3]=0.f;}

        for (int sc=0; sc<8; ++sc){
            const float* src = hcur + (size_t)(kbase + sc*32)*64;
            float* dst = hstage[wave];
            #pragma unroll
            for (int i=0;i<8;++i)
                *reinterpret_cast<float4*>(&dst[i*256 + lane*4]) =
                    *reinterpret_cast<const float4*>(&src[i*256 + lane*4]);
            const float* wl = &Wlds[(size_t)(kbase + sc*32)*16];
            #pragma unroll
            for (int kk=0; kk<32; ++kk){
                float4 hv = *reinterpret_cast<float4*>(&hstage[wave][kk*64 + b0]);
                float4 wv = *reinterpret_cast<const float4*>(&wl[kk*16 + c0]);
                acc[0][0]+=hv.x*wv.x; acc[0][1]+=hv.x*wv.y; acc[0][2]+=hv.x*wv.z; acc[0][3]+=hv.x*wv.w;
                acc[1][0]+=hv.y*wv.x; acc[1][1]+=hv.y*wv.y; acc[1][2]+=hv.y*wv.z; acc[1][3]+=hv.y*wv.w;
                acc[2][0]+=hv.z*wv.x; acc[2][1]+=hv.z*wv.y; acc[2][2]+=hv.z*wv.z; acc[2][3]+=hv.z*wv.w;
                acc[3][0]+=hv.w*wv.x; acc[3][1]+=hv.w*wv.y; acc[3][2]+=hv.w*wv.z; acc[3][3]+=hv.w*wv.w;
            }
        }
        #pragma unroll
        for (int bi=0;bi<4;++bi)
            *reinterpret_cast<float4*>(&pacc[wave][(b0+bi)*16 + c0]) =
                make_float4(acc[bi][0],acc[bi][1],acc[bi][2],acc[bi][3]);
        __syncthreads();

        // phase C: one thread per (batch, h-col)
        {
            float gs[4];
            #pragma unroll
            for (int g=0; g<4; ++g){
                int idx = bq*16 + g*4 + hj;
                gs[g] = xwlds[idx] + pacc[0][idx] + pacc[1][idx] + pacc[2][idx] + pacc[3][idx];
            }
            float ig = 1.f/(1.f + __expf(-gs[0]));
            float fg = 1.f/(1.f + __expf(-gs[1]));
            float gg = tanhf(gs[2]);
            float og = 1.f/(1.f + __expf(-gs[3]));
            const int hcolg = bidx*4 + hj;
            float c_new = fg * ct[hcolg*64 + bq] + ig * gg;
            float h_new = og * tanhf(c_new);
            ct[hcolg*64 + bq] = c_new;
            hnxt[hcolg*64 + bq] = h_new;
            hout[bq*4 + hj] = h_new;
            if (t == TSTEPS-1){
                hn[(size_t)bq*1024 + hcolg] = h_new;
                cn[(size_t)bq*1024 + hcolg] = c_new;
            }
        }
        __syncthreads();
        if (tid < 64){
            float4 hv = *reinterpret_cast<float4*>(&hout[tid*4]);
            *reinterpret_cast<float4*>(&out[(size_t)t*65536 + (size_t)tid*1024 + bidx*4]) = hv;
        }
        cg::this_grid().sync();
        float* tmp = hcur; hcur = hnxt; hnxt = tmp;
    }
}

// ---------------------------------------------------------------------------
template<typename GT>
static void run_all(const float* x, const float* Wih0, const float* Whh0, const float* b0,
                    const float* Wih1, const float* Whh1, const float* b1,
                    float* out1, float* hn, float* cn,
                    char* wsb, hipStream_t stream)
{
    const size_t gelems = (size_t)NROWS * 4096;
    GT*    gpbuf = (GT*)wsb;
    float* out0  = (float*)(wsb + gelems*sizeof(GT));
    float* hta   = out0 + (size_t)NROWS*HDIM;
    float* htb   = hta + 65536;
    float* ctb   = htb + 65536;

    dim3 ggrid(32, 256), gblk(256);
    dim3 rgrid(256), rblk(256);

    hipLaunchKernelGGL((gemm_xw<GT>), ggrid, gblk, 0, stream, x, Wih0, b0, gpbuf);
    {
        const GT* gpc = gpbuf; const float* whh = Whh0;
        float* op = out0; float* ha = hta; float* hb = htb; float* cc = ctb;
        float* h_ = hn; float* c_ = cn;
        void* args[8] = {(void*)&gpc, (void*)&whh, (void*)&op, (void*)&ha,
                         (void*)&hb, (void*)&cc, (void*)&h_, (void*)&c_};
        hipLaunchCooperativeKernel(reinterpret_cast<void*>(&lstm_seq<GT>),
                                   rgrid, rblk, args, 0, stream);
    }
    hipLaunchKernelGGL((gemm_xw<GT>), ggrid, gblk, 0, stream, out0, Wih1, b1, gpbuf);
    {
        const GT* gpc = gpbuf; const float* whh = Whh1;
        float* op = out1; float* ha = hta; float* hb = htb; float* cc = ctb;
        float* h_ = hn + 65536; float* c_ = cn + 65536;
        void* args[8] = {(void*)&gpc, (void*)&whh, (void*)&op, (void*)&ha,
                         (void*)&hb, (void*)&cc, (void*)&h_, (void*)&c_};
        hipLaunchCooperativeKernel(reinterpret_cast<void*>(&lstm_seq<GT>),
                                   rgrid, rblk, args, 0, stream);
    }
}

extern "C" void kernel_launch(void* const* d_in, const int* in_sizes, int n_in,
                              void* d_out, int out_size, void* d_ws, size_t ws_size,
                              hipStream_t stream)
{
    const float* x    = (const float*)d_in[0];
    const float* Wih0 = (const float*)d_in[1];
    const float* Whh0 = (const float*)d_in[2];
    const float* b0   = (const float*)d_in[3];
    const float* Wih1 = (const float*)d_in[4];
    const float* Whh1 = (const float*)d_in[5];
    const float* b1   = (const float*)d_in[6];

    float* out1 = (float*)d_out;
    float* hn   = out1 + (size_t)NROWS*HDIM;      // [2][64][1024]
    float* cn   = hn + 2*BATCH*HDIM;

    // ws need: gates buffer + out0 + 3 small h/c buffers
    const size_t rest_bytes = ((size_t)NROWS*HDIM + 3*65536) * 4;
    const size_t need_f32 = (size_t)NROWS*4096*4 + rest_bytes;
    char* wsb = (char*)d_ws;

    if (ws_size >= need_f32){
        run_all<float>(x, Wih0, Whh0, b0, Wih1, Whh1, b1, out1, hn, cn, wsb, stream);
    } else {
        run_all<unsigned short>(x, Wih0, Whh0, b0, Wih1, Whh1, b1, out1, hn, cn, wsb, stream);
    }
}

// Round 4
// 57078.333 us; speedup vs baseline: 1.1953x; 1.1953x over previous
//
#include <hip/hip_runtime.h>
#include <hip/hip_bf16.h>

#define TSTEPS 512
#define NSTEPS 256          // steps per chunk
#define BATCH  64
#define HDIM   1024
#define NROWS  (TSTEPS*BATCH)   // 32768

typedef __attribute__((ext_vector_type(8))) short bf16x8;
typedef __attribute__((ext_vector_type(4))) float f32x4;

__device__ __forceinline__ unsigned short f2bf(float f){
    unsigned u = __float_as_uint(f);
    u += 0x7fffu + ((u >> 16) & 1u);
    return (unsigned short)(u >> 16);
}
__device__ __forceinline__ float bf2f(unsigned short s){
    return __uint_as_float(((unsigned)s) << 16);
}

// ---------------------------------------------------------------------------
// Grid barrier: fresh counter per use (no ABA). Explicit agent-scope
// release/acquire fences so h-buffer stores are cross-XCD visible.
// ---------------------------------------------------------------------------
__device__ __forceinline__ void gridbar(unsigned int* c, unsigned int nblk){
    __syncthreads();
    if (threadIdx.x == 0){
        __builtin_amdgcn_fence(__ATOMIC_RELEASE, "agent");   // wb L2
        __hip_atomic_fetch_add(c, 1u, __ATOMIC_RELAXED, __HIP_MEMORY_SCOPE_AGENT);
        while (__hip_atomic_load(c, __ATOMIC_RELAXED, __HIP_MEMORY_SCOPE_AGENT) != nblk)
            __builtin_amdgcn_s_sleep(1);
        __builtin_amdgcn_fence(__ATOMIC_ACQUIRE, "agent");   // inv L1/L2
    }
    __syncthreads();
    __builtin_amdgcn_fence(__ATOMIC_ACQUIRE, "agent");
}

// ---------------------------------------------------------------------------
// W [1024][4096] fp32 -> WThi/WTlo [4096][1024] bf16 (transpose + split)
// ---------------------------------------------------------------------------
__global__ __launch_bounds__(256)
void split_transpose_w(const float* __restrict__ W,
                       unsigned short* __restrict__ WThi,
                       unsigned short* __restrict__ WTlo)
{
    __shared__ float tile[32][33];
    const int c0 = blockIdx.x * 32;
    const int k0 = blockIdx.y * 32;
    const int tx = threadIdx.x & 31, ty = threadIdx.x >> 5;
    #pragma unroll
    for (int r=0;r<4;++r)
        tile[ty + r*8][tx] = W[(size_t)(k0 + ty + r*8)*4096 + c0 + tx];
    __syncthreads();
    #pragma unroll
    for (int r=0;r<4;++r){
        float v = tile[tx][ty + r*8];
        unsigned short hi = f2bf(v);
        unsigned short lo = f2bf(v - bf2f(hi));
        WThi[(size_t)(c0 + ty + r*8)*1024 + k0 + tx] = hi;
        WTlo[(size_t)(c0 + ty + r*8)*1024 + k0 + tx] = lo;
    }
}

// ---------------------------------------------------------------------------
// Split-bf16 MFMA GEMM over one 16384-row chunk:
//   gp[t][bid][b][j] = sum_k A[row][k]*W[k][col] + bias[col]
// A fp32 (reg-staged, split hi/lo in-kernel), W pre-split bf16 [4096][1024].
// col = g*1024 + bid*4 + hj, j = g*4 + hj. 128x128 tile, BK=32, 4 waves.
// ---------------------------------------------------------------------------
__global__ __launch_bounds__(256)
void gemm_xw_split(const float* __restrict__ A,
                   const unsigned short* __restrict__ BThi,
                   const unsigned short* __restrict__ BTlo,
                   const float* __restrict__ bias, float* __restrict__ gp)
{
    __shared__ __align__(16) unsigned short Ahi[128*32];
    __shared__ __align__(16) unsigned short Alo[128*32];
    __shared__ __align__(16) unsigned short Bhi[128*32];
    __shared__ __align__(16) unsigned short Blo[128*32];

    const int tid = threadIdx.x;
    const int w = tid >> 6, l = tid & 63;
    const int bx = blockIdx.x & 31, by = blockIdx.x >> 5;   // 32 n-tiles, 128 m-tiles
    const int row0 = by*128, col0 = bx*128;
    const int wrow = (w>>1)*64, wcol = (w&1)*64;

    const int srow  = l >> 2;
    const int skoff = (l & 3) * 8;

    const int arow  = tid >> 1;
    const int akoff = (tid & 1) * 16;
    const float* aptr = A + (size_t)(row0 + arow)*1024 + akoff;

    f32x4 acc[4][4];
    #pragma unroll
    for (int m=0;m<4;++m)
        #pragma unroll
        for (int n=0;n<4;++n)
            acc[m][n] = (f32x4){0.f,0.f,0.f,0.f};

    for (int k0=0; k0<1024; k0+=32){
        #pragma unroll
        for (int c=0;c<2;++c){
            const int i = w*2 + c;
            const unsigned short* gh = BThi + (size_t)(col0 + i*16 + srow)*1024 + k0 + skoff;
            const unsigned short* gl = BTlo + (size_t)(col0 + i*16 + srow)*1024 + k0 + skoff;
            __builtin_amdgcn_global_load_lds((const __attribute__((address_space(1))) void*)gh,
                (__attribute__((address_space(3))) void*)(Bhi + i*512), 16, 0, 0);
            __builtin_amdgcn_global_load_lds((const __attribute__((address_space(1))) void*)gl,
                (__attribute__((address_space(3))) void*)(Blo + i*512), 16, 0, 0);
        }
        {
            float4 x0 = *reinterpret_cast<const float4*>(aptr + k0);
            float4 x1 = *reinterpret_cast<const float4*>(aptr + k0 + 4);
            float4 x2 = *reinterpret_cast<const float4*>(aptr + k0 + 8);
            float4 x3 = *reinterpret_cast<const float4*>(aptr + k0 + 12);
            float xs[16] = {x0.x,x0.y,x0.z,x0.w, x1.x,x1.y,x1.z,x1.w,
                            x2.x,x2.y,x2.z,x2.w, x3.x,x3.y,x3.z,x3.w};
            unsigned short hs[16], ls[16];
            #pragma unroll
            for (int e=0;e<16;++e){
                hs[e] = f2bf(xs[e]);
                ls[e] = f2bf(xs[e] - bf2f(hs[e]));
            }
            #pragma unroll
            for (int q=0;q<4;++q){
                ushort4 h4; h4.x=hs[q*4]; h4.y=hs[q*4+1]; h4.z=hs[q*4+2]; h4.w=hs[q*4+3];
                ushort4 l4; l4.x=ls[q*4]; l4.y=ls[q*4+1]; l4.z=ls[q*4+2]; l4.w=ls[q*4+3];
                *reinterpret_cast<ushort4*>(&Ahi[arow*32 + akoff + q*4]) = h4;
                *reinterpret_cast<ushort4*>(&Alo[arow*32 + akoff + q*4]) = l4;
            }
        }
        __syncthreads();
        bf16x8 afh[4], afl[4], bfh[4], bfl[4];
        #pragma unroll
        for (int m=0;m<4;++m){
            const int off = (wrow + m*16 + (l&15))*32 + (l>>4)*8;
            afh[m] = *reinterpret_cast<const bf16x8*>(&Ahi[off]);
            afl[m] = *reinterpret_cast<const bf16x8*>(&Alo[off]);
        }
        #pragma unroll
        for (int n=0;n<4;++n){
            const int off = (wcol + n*16 + (l&15))*32 + (l>>4)*8;
            bfh[n] = *reinterpret_cast<const bf16x8*>(&Bhi[off]);
            bfl[n] = *reinterpret_cast<const bf16x8*>(&Blo[off]);
        }
        #pragma unroll
        for (int m=0;m<4;++m)
            #pragma unroll
            for (int n=0;n<4;++n){
                acc[m][n] = __builtin_amdgcn_mfma_f32_16x16x32_bf16(afh[m], bfh[n], acc[m][n], 0,0,0);
                acc[m][n] = __builtin_amdgcn_mfma_f32_16x16x32_bf16(afl[m], bfh[n], acc[m][n], 0,0,0);
                acc[m][n] = __builtin_amdgcn_mfma_f32_16x16x32_bf16(afh[m], bfl[n], acc[m][n], 0,0,0);
            }
        __syncthreads();
    }

    #pragma unroll
    for (int n=0;n<4;++n){
        const int n_g = col0 + wcol + n*16 + (l&15);
        const float bv = bias[n_g];
        const int g = n_g >> 10, hcol = n_g & 1023;
        const int bid = hcol >> 2, hj = hcol & 3;
        #pragma unroll
        for (int m=0;m<4;++m){
            #pragma unroll
            for (int r=0;r<4;++r){
                const int m_g = row0 + wrow + m*16 + (l>>4)*4 + r;
                const int t = m_g >> 6, b = m_g & 63;    // t local to chunk
                gp[(((size_t)t*256 + bid)*64 + b)*16 + g*4 + hj] = acc[m][n][r] + bv;
            }
        }
    }
}

// ---------------------------------------------------------------------------
// Persistent recurrence over one 256-step chunk — ALL fp32.
// Block owns h-cols [bidx*4, bidx*4+4). W_hh slice in LDS; h fp32 [1024][64]
// double-buffered in global (even #steps -> state ends back in hta);
// c in LDS, saved/restored via ctg between chunks.
// ---------------------------------------------------------------------------
__global__ __launch_bounds__(256)
void lstm_seq(const float* __restrict__ gp, const float* __restrict__ Whh,
              float* __restrict__ out, float* __restrict__ hta,
              float* __restrict__ htb, float* __restrict__ ctg,
              float* __restrict__ hn, float* __restrict__ cn,
              unsigned int* __restrict__ bar, int first, int last)
{
    __shared__ float Wlds[1024*16];        // 64 KB [k][j]
    __shared__ float hstage[4][2][2048];   // 64 KB per-wave dbuf [32k][64b]
    __shared__ float pacc[4][64*17];       // padded partial gates [b][j]
    __shared__ float xwlds[64*17];         // padded xW slice [b][j]
    __shared__ float ctl[256];             // c state [hj*64+b]
    __shared__ float hout[256];            // h_new [b*4+hj]

    const int tid  = threadIdx.x;
    const int bidx = blockIdx.x;
    const int w = tid >> 6, l = tid & 63;

    {   // W_hh slice: Wlds[k][j] = Whh[k][(j/4)*1024 + bidx*4 + (j%4)]
        const int j = tid & 15;
        const int col = (j>>2)*1024 + bidx*4 + (j&3);
        for (int k = tid>>4; k < 1024; k += 16)
            Wlds[k*16 + j] = Whh[(size_t)k*4096 + col];
    }
    ctl[tid] = first ? 0.f : ctg[bidx*256 + tid];
    if (first){
        const int hcolg = bidx*4 + (tid>>6);
        hta[hcolg*64 + (tid&63)] = 0.f;
        gridbar(bar, 256);
    }

    float* hcur = hta;
    float* hnxt = htb;

    const int c0 = (l & 3) << 2;
    const int b0 = (l >> 2) << 2;
    const int kbase = w << 8;
    const int bq = tid & 63;
    const int hj = tid >> 6;

    for (int t=0; t<NSTEPS; ++t){
        {   // xW[t] slice -> xwlds (padded [b][j], stride 17)
            float4 v = *reinterpret_cast<const float4*>(gp + ((size_t)t*256 + bidx)*1024 + tid*4);
            const int b = tid >> 2, j0 = (tid & 3)*4;
            float* xp = &xwlds[b*17 + j0];
            xp[0]=v.x; xp[1]=v.y; xp[2]=v.z; xp[3]=v.w;
        }

        const float* hc = hcur + (size_t)kbase*64;
        float4 pre[8];
        #pragma unroll
        for (int it=0;it<8;++it)
            pre[it] = *reinterpret_cast<const float4*>(hc + it*256 + l*4);
        #pragma unroll
        for (int it=0;it<8;++it)
            *reinterpret_cast<float4*>(&hstage[w][0][it*256 + l*4]) = pre[it];

        float acc[4][4];
        #pragma unroll
        for (int i2=0;i2<4;++i2){acc[i2][0]=0.f;acc[i2][1]=0.f;acc[i2][2]=0.f;acc[i2][3]=0.f;}

        for (int sc=0; sc<8; ++sc){
            if (sc < 7){
                const float* s2 = hc + (size_t)(sc+1)*2048;
                #pragma unroll
                for (int it=0;it<8;++it)
                    pre[it] = *reinterpret_cast<const float4*>(s2 + it*256 + l*4);
            }
            const float* hs = hstage[w][sc&1];
            const float* wl = &Wlds[(size_t)(kbase + sc*32)*16];
            #pragma unroll
            for (int kk=0; kk<32; ++kk){
                float4 hv = *reinterpret_cast<const float4*>(&hs[kk*64 + b0]);
                float4 wv = *reinterpret_cast<const float4*>(&wl[kk*16 + c0]);
                acc[0][0]+=hv.x*wv.x; acc[0][1]+=hv.x*wv.y; acc[0][2]+=hv.x*wv.z; acc[0][3]+=hv.x*wv.w;
                acc[1][0]+=hv.y*wv.x; acc[1][1]+=hv.y*wv.y; acc[1][2]+=hv.y*wv.z; acc[1][3]+=hv.y*wv.w;
                acc[2][0]+=hv.z*wv.x; acc[2][1]+=hv.z*wv.y; acc[2][2]+=hv.z*wv.z; acc[2][3]+=hv.z*wv.w;
                acc[3][0]+=hv.w*wv.x; acc[3][1]+=hv.w*wv.y; acc[3][2]+=hv.w*wv.z; acc[3][3]+=hv.w*wv.w;
            }
            if (sc < 7){
                float* d = hstage[w][(sc+1)&1];
                #pragma unroll
                for (int it=0;it<8;++it)
                    *reinterpret_cast<float4*>(&d[it*256 + l*4]) = pre[it];
            }
        }
        #pragma unroll
        for (int bi=0;bi<4;++bi){
            float* pp = &pacc[w][(b0+bi)*17 + c0];
            pp[0]=acc[bi][0]; pp[1]=acc[bi][1]; pp[2]=acc[bi][2]; pp[3]=acc[bi][3];
        }
        __syncthreads();

        {   // phase C: one thread per (batch, h-col)
            float gs[4];
            #pragma unroll
            for (int g=0; g<4; ++g){
                const int idx = bq*17 + g*4 + hj;
                gs[g] = xwlds[idx] + pacc[0][idx] + pacc[1][idx] + pacc[2][idx] + pacc[3][idx];
            }
            float ig = 1.f/(1.f + __expf(-gs[0]));
            float fg = 1.f/(1.f + __expf(-gs[1]));
            float gg = tanhf(gs[2]);
            float og = 1.f/(1.f + __expf(-gs[3]));
            float c_new = fg * ctl[hj*64 + bq] + ig * gg;
            float h_new = og * tanhf(c_new);
            ctl[hj*64 + bq] = c_new;
            const int hcolg = bidx*4 + hj;
            hnxt[hcolg*64 + bq] = h_new;
            hout[bq*4 + hj] = h_new;
            if (last && t == NSTEPS-1){
                hn[(size_t)bq*1024 + hcolg] = h_new;
                cn[(size_t)bq*1024 + hcolg] = c_new;
            }
        }
        __syncthreads();
        if (tid < 64){
            float4 hv = *reinterpret_cast<const float4*>(&hout[tid*4]);
            *reinterpret_cast<float4*>(&out[(size_t)t*65536 + (size_t)tid*1024 + bidx*4]) = hv;
        }
        gridbar(bar + 1 + t, 256);
        float* tmp = hcur; hcur = hnxt; hnxt = tmp;
    }
    ctg[bidx*256 + tid] = ctl[tid];
}

// ---------------------------------------------------------------------------
extern "C" void kernel_launch(void* const* d_in, const int* in_sizes, int n_in,
                              void* d_out, int out_size, void* d_ws, size_t ws_size,
                              hipStream_t stream)
{
    const float* x    = (const float*)d_in[0];
    const float* Wih0 = (const float*)d_in[1];
    const float* Whh0 = (const float*)d_in[2];
    const float* b0   = (const float*)d_in[3];
    const float* Wih1 = (const float*)d_in[4];
    const float* Whh1 = (const float*)d_in[5];
    const float* b1   = (const float*)d_in[6];

    float* out1 = (float*)d_out;
    float* hn   = out1 + (size_t)NROWS*HDIM;      // [2][64][1024]
    float* cn   = hn + 2*BATCH*HDIM;

    // layer-0 output scratch aliases out1 (chunk ordering makes this safe:
    // each out0 chunk is consumed by the layer-1 GEMM before the layer-1
    // recurrence overwrites that region).
    float* out0 = out1;

    char* wsb = (char*)d_ws;
    float*          gp    = (float*)wsb;                               // 268,435,456 B
    unsigned short* WThi0 = (unsigned short*)(wsb + 268435456ull);     //   8,388,608
    unsigned short* WTlo0 = (unsigned short*)(wsb + 276824064ull);     //   8,388,608
    unsigned short* WThi1 = (unsigned short*)(wsb + 285212672ull);     //   8,388,608
    unsigned short* WTlo1 = (unsigned short*)(wsb + 293601280ull);     //   8,388,608
    float*          hta   = (float*)(wsb + 301989888ull);              //     262,144
    float*          htb   = (float*)(wsb + 302252032ull);              //     262,144
    float*          ctg   = (float*)(wsb + 302514176ull);              //     262,144
    unsigned int*   bar   = (unsigned int*)(wsb + 302776320ull);       //       4,112

    hipMemsetAsync(bar, 0, 1028*sizeof(unsigned int), stream);
    split_transpose_w<<<dim3(128,32),256,0,stream>>>(Wih0, WThi0, WTlo0);
    split_transpose_w<<<dim3(128,32),256,0,stream>>>(Wih1, WThi1, WTlo1);

    const float*          Ain [2] = {x, out0};
    const unsigned short* Whi [2] = {WThi0, WThi1};
    const unsigned short* Wlo [2] = {WTlo0, WTlo1};
    const float*          bia [2] = {b0, b1};
    const float*          whh [2] = {Whh0, Whh1};
    float*                outp[2] = {out0, out1};

    for (int layer=0; layer<2; ++layer){
        for (int chunk=0; chunk<2; ++chunk){
            gemm_xw_split<<<4096,256,0,stream>>>(
                Ain[layer] + (size_t)chunk*NSTEPS*BATCH*HDIM,
                Whi[layer], Wlo[layer], bia[layer], gp);

            const float* gpc = gp; const float* wh = whh[layer];
            float* op = outp[layer] + (size_t)chunk*NSTEPS*BATCH*HDIM;
            float* ha = hta; float* hb = htb; float* cg_ = ctg;
            float* h_ = hn + (size_t)layer*BATCH*HDIM;
            float* c_ = cn + (size_t)layer*BATCH*HDIM;
            unsigned int* br = bar + (size_t)(layer*2 + chunk)*257;
            int first = (chunk == 0), last = (chunk == 1);
            void* args[11] = {(void*)&gpc, (void*)&wh, (void*)&op, (void*)&ha,
                              (void*)&hb, (void*)&cg_, (void*)&h_, (void*)&c_,
                              (void*)&br, (void*)&first, (void*)&last};
            hipLaunchCooperativeKernel(reinterpret_cast<void*>(&lstm_seq),
                                       dim3(256), dim3(256), args, 0, stream);
        }
    }
}